// Round 5
// baseline (136.836 us; speedup 1.0000x reference)
//
#include <hip/hip_runtime.h>
#include <hip/hip_bf16.h>
#include <cstdint>

// Problem: B=64, D=1024, H=1024.
// act columns (6144): [0,1024) i_g | [1024,2048) f_g | [2048,3072) o_g
//                     [3072,4096) q | [4096,5120) k  | [5120,6144) v

#define NCOL 6144

typedef __attribute__((ext_vector_type(8))) short short8;
typedef __attribute__((ext_vector_type(4))) float f32x4;
typedef __attribute__((ext_vector_type(4))) unsigned short u16x4;

static __device__ __forceinline__ unsigned short f2b(float f) {
    union { float f; uint32_t u; } v; v.f = f;
    uint32_t r = (v.u + 0x7FFFu + ((v.u >> 16) & 1u)) >> 16;  // RNE
    return (unsigned short)r;
}

// ---------------- Kernel C: convert input/h to bf16 (tiny) ----------------
__global__ __launch_bounds__(256) void cvt_kernel(
    const float* __restrict__ x, const float* __restrict__ h,
    unsigned short* __restrict__ xbf, unsigned short* __restrict__ hbf)
{
    int i = blockIdx.x * 256 + threadIdx.x;          // 0..16383
    const float* s = (i < 8192) ? x : h;
    unsigned short* d = (i < 8192) ? xbf : hbf;
    int j = (i & 8191) * 8;
    f32x4 a = *(const f32x4*)&s[j];
    f32x4 b = *(const f32x4*)&s[j + 4];
    u16x4 ua, ub;
    ua[0]=f2b(a[0]); ua[1]=f2b(a[1]); ua[2]=f2b(a[2]); ua[3]=f2b(a[3]);
    ub[0]=f2b(b[0]); ub[1]=f2b(b[1]); ub[2]=f2b(b[2]); ub[3]=f2b(b[3]);
    *(u16x4*)&d[j] = ua;
    *(u16x4*)&d[j + 4] = ub;
}

// ---------------- Kernel P: projections, zero-LDS direct-fragment MFMA ------
// grid: (96 col-tiles, 8 K-chunks of 256), 256 threads = 4 waves.
// Wave w owns cols jbase+w*16..+15. Fragments loaded straight from global:
//   B-frag: W rows (fp32, two f32x4 per lane, 128B strips) -> cvt to bf16
//   A-frag: Xbf/Hbf (bf16, one short8 per lane, L2/L3-resident)
// part layout: part[c][b][j]
__global__ __launch_bounds__(256) void proj_kernel(
    const unsigned short* __restrict__ Xbf, const unsigned short* __restrict__ Hbf,
    const float* __restrict__ w_ih, const float* __restrict__ w_hh,
    const float* __restrict__ wq, const float* __restrict__ wk,
    const float* __restrict__ wv, float* __restrict__ part)
{
    int ct = blockIdx.x;            // 0..95
    int c  = blockIdx.y;            // 0..7
    int jbase = ct * 64;
    int o = jbase >> 10;            // 0..5
    if (o >= 3 && c >= 4) return;   // q/k/v have K=1024 (4 chunks)
    int jloc = jbase & 1023;

    const float* W; const unsigned short* A; int koff; int wrow;
    if (o < 3) {
        wrow = o * 1024 + jloc;
        if (c < 4) { W = w_ih; A = Xbf; koff = c * 256; }
        else       { W = w_hh; A = Hbf; koff = (c - 4) * 256; }
    } else {
        wrow = jloc;
        W = (o == 3) ? wq : (o == 4) ? wk : wv;
        A = Xbf; koff = c * 256;
    }

    int tid = threadIdx.x;
    int lane = tid & 63;
    int w    = tid >> 6;            // wave -> col group
    int cn16 = lane & 15;
    int kg   = lane >> 4;           // 0..3

    const float* wptr = W + (size_t)(wrow + w * 16 + cn16) * 1024 + koff + kg * 8;
    const unsigned short* abase = A + koff + kg * 8;

    f32x4 acc[4];
    #pragma unroll
    for (int m = 0; m < 4; ++m) { acc[m][0]=0.f; acc[m][1]=0.f; acc[m][2]=0.f; acc[m][3]=0.f; }

    #pragma unroll
    for (int ks = 0; ks < 8; ++ks) {
        f32x4 w0 = *(const f32x4*)(wptr + ks * 32);
        f32x4 w1 = *(const f32x4*)(wptr + ks * 32 + 4);
        short8 bf;
        bf[0]=f2b(w0[0]); bf[1]=f2b(w0[1]); bf[2]=f2b(w0[2]); bf[3]=f2b(w0[3]);
        bf[4]=f2b(w1[0]); bf[5]=f2b(w1[1]); bf[6]=f2b(w1[2]); bf[7]=f2b(w1[3]);
        #pragma unroll
        for (int m = 0; m < 4; ++m) {
            short8 af = *(const short8*)(abase + (size_t)(m * 16 + cn16) * 1024 + ks * 32);
            acc[m] = __builtin_amdgcn_mfma_f32_16x16x32_bf16(af, bf, acc[m], 0, 0, 0);
        }
    }

    // D layout: col = lane&15, row(batch) = kg*4 + reg (+ m*16)
    #pragma unroll
    for (int m = 0; m < 4; ++m) {
        #pragma unroll
        for (int r = 0; r < 4; ++r) {
            int b = m * 16 + kg * 4 + r;
            part[((size_t)c * 64 + b) * NCOL + jbase + w * 16 + cn16] = acc[m][r];
        }
    }
}

// ---------------- Kernel A: reduce chunks + bias + activation (float4) ------
__global__ __launch_bounds__(256) void act_kernel(
    const float* __restrict__ part, const float* __restrict__ bias,
    const float* __restrict__ wq_b, const float* __restrict__ wk_b,
    const float* __restrict__ wv_b, float* __restrict__ act)
{
    int idx4 = blockIdx.x * 256 + threadIdx.x;   // 0..64*6144/4
    int b = idx4 / (NCOL / 4);
    int j = (idx4 - b * (NCOL / 4)) * 4;
    int nc = (j < 3072) ? 8 : 4;
    f32x4 s; s[0]=0.f; s[1]=0.f; s[2]=0.f; s[3]=0.f;
    for (int cc = 0; cc < nc; ++cc)
        s += *(const f32x4*)&part[((size_t)cc * 64 + b) * NCOL + j];
    const float* bp;
    if (j < 3072) bp = bias + j;
    else if (j < 4096) bp = wq_b + (j - 3072);
    else if (j < 5120) bp = wk_b + (j - 4096);
    else bp = wv_b + (j - 5120);
    s += *(const f32x4*)bp;
    f32x4 r;
    if (j < 2048) {
        r[0] = expf(s[0]); r[1] = expf(s[1]); r[2] = expf(s[2]); r[3] = expf(s[3]);
    } else if (j < 3072) {
        r[0] = 1.f/(1.f+expf(-s[0])); r[1] = 1.f/(1.f+expf(-s[1]));
        r[2] = 1.f/(1.f+expf(-s[2])); r[3] = 1.f/(1.f+expf(-s[3]));
    } else {
        r = s;
    }
    *(f32x4*)&act[(size_t)b * NCOL + j] = r;
}

// ---------------- Kernel U: c_new = f*c + (i*v)*k, fused q-weighted row sums -
// grid: (16 row-tiles of 64, 64 batches), 256 threads, 4 cols/thread.
__global__ __launch_bounds__(256) void update_kernel(
    const float* __restrict__ c_in, const float* __restrict__ act,
    float* __restrict__ c_out, float* __restrict__ hpart)
{
    int t = blockIdx.x;            // 0..15
    int b = blockIdx.y;            // 0..63
    int tid = threadIdx.x;
    const float* arow = act + (size_t)b * NCOL;

    __shared__ float fs[64], ivs[64], qvs[64];
    if (tid < 64) {
        int hrow = t * 64 + tid;
        fs[tid]  = arow[1024 + hrow];
        ivs[tid] = arow[hrow] * arow[5120 + hrow];
        qvs[tid] = arow[3072 + hrow];
    }
    int col = tid * 4;
    f32x4 k4 = *(const f32x4*)&arow[4096 + col];
    __syncthreads();

    f32x4 acc; acc[0]=0.f; acc[1]=0.f; acc[2]=0.f; acc[3]=0.f;
    size_t base = ((size_t)b * 1024 + (size_t)t * 64) * 1024 + col;

    #pragma unroll 8
    for (int hh = 0; hh < 64; ++hh) {
        f32x4 c4 = __builtin_nontemporal_load((const f32x4*)(c_in + base + (size_t)hh * 1024));
        float f = fs[hh], iv = ivs[hh], qv = qvs[hh];
        f32x4 cn = f * c4 + iv * k4;
        __builtin_nontemporal_store(cn, (f32x4*)(c_out + base + (size_t)hh * 1024));
        acc += qv * cn;
    }
    *(f32x4*)&hpart[((size_t)b * 16 + t) * 1024 + col] = acc;
}

// ---------------- Kernel R: h_new = o_g * sum_t hpart ----------------
__global__ __launch_bounds__(256) void readout_kernel(
    const float* __restrict__ hpart, const float* __restrict__ act,
    float* __restrict__ h_new)
{
    int idx = blockIdx.x * 256 + threadIdx.x;   // 0..65536
    int b = idx >> 10, j = idx & 1023;
    float s = 0.f;
    #pragma unroll
    for (int t = 0; t < 16; ++t)
        s += hpart[((size_t)b * 16 + t) * 1024 + j];
    h_new[idx] = act[(size_t)b * NCOL + 2048 + j] * s;
}

extern "C" void kernel_launch(void* const* d_in, const int* in_sizes, int n_in,
                              void* d_out, int out_size, void* d_ws, size_t ws_size,
                              hipStream_t stream)
{
    (void)in_sizes; (void)n_in; (void)out_size; (void)ws_size;
    const float* input = (const float*)d_in[0];   // [64,1024]
    const float* hvec  = (const float*)d_in[1];   // [64,1024]
    const float* c_in  = (const float*)d_in[2];   // [64,1024,1024]
    const float* w_ih  = (const float*)d_in[3];   // [3072,1024]
    const float* w_hh  = (const float*)d_in[4];   // [3072,1024]
    const float* bias  = (const float*)d_in[5];   // [3072]
    const float* wq_w  = (const float*)d_in[6];   // [1024,1024]
    const float* wq_b  = (const float*)d_in[7];
    const float* wk_w  = (const float*)d_in[8];
    const float* wk_b  = (const float*)d_in[9];
    const float* wv_w  = (const float*)d_in[10];
    const float* wv_b  = (const float*)d_in[11];

    float* out   = (float*)d_out;
    float* h_new = out;                 // [64,1024]
    float* c_new = out + 64 * 1024;     // [64,1024,1024]

    float* ws    = (float*)d_ws;
    float* part  = ws;                                   // 8*64*6144 floats
    float* act   = part + (size_t)8 * 64 * NCOL;         // 64*6144
    float* hpart = act + (size_t)64 * NCOL;              // 64*16*1024
    unsigned short* xbf = (unsigned short*)(hpart + (size_t)64 * 16 * 1024);
    unsigned short* hbf = xbf + 64 * 1024;

    cvt_kernel<<<64, 256, 0, stream>>>(input, hvec, xbf, hbf);
    proj_kernel<<<dim3(96, 8), 256, 0, stream>>>(xbf, hbf, w_ih, w_hh,
                                                 wq_w, wk_w, wv_w, part);
    act_kernel<<<(64 * NCOL / 4) / 256, 256, 0, stream>>>(part, bias, wq_b, wk_b,
                                                          wv_b, act);
    update_kernel<<<dim3(16, 64), 256, 0, stream>>>(c_in, act, c_new, hpart);
    readout_kernel<<<(64 * 1024) / 256, 256, 0, stream>>>(hpart, act, h_new);
}

// Round 6
// 133.636 us; speedup vs baseline: 1.0239x; 1.0239x over previous
//
#include <hip/hip_runtime.h>
#include <hip/hip_bf16.h>
#include <cstdint>

// Problem: B=64, D=1024, H=1024.
// part columns (6144): [0,1024) i_g | [1024,2048) f_g | [2048,3072) o_g
//                      [3072,4096) q | [4096,5120) k  | [5120,6144) v
// part layout: part[c][b][j], c = K-chunk (8 chunks of 256; qkv use c<4)

#define NCOL 6144

typedef __attribute__((ext_vector_type(8))) short short8;
typedef __attribute__((ext_vector_type(4))) float f32x4;
typedef __attribute__((ext_vector_type(4))) unsigned short u16x4;

static __device__ __forceinline__ unsigned short f2b(float f) {
    union { float f; uint32_t u; } v; v.f = f;
    uint32_t r = (v.u + 0x7FFFu + ((v.u >> 16) & 1u)) >> 16;  // RNE
    return (unsigned short)r;
}

// ---------------- Kernel C: convert input/h to bf16 (tiny) ----------------
__global__ __launch_bounds__(256) void cvt_kernel(
    const float* __restrict__ x, const float* __restrict__ h,
    unsigned short* __restrict__ xbf, unsigned short* __restrict__ hbf)
{
    int i = blockIdx.x * 256 + threadIdx.x;          // 0..16383
    const float* s = (i < 8192) ? x : h;
    unsigned short* d = (i < 8192) ? xbf : hbf;
    int j = (i & 8191) * 8;
    f32x4 a = *(const f32x4*)&s[j];
    f32x4 b = *(const f32x4*)&s[j + 4];
    u16x4 ua, ub;
    ua[0]=f2b(a[0]); ua[1]=f2b(a[1]); ua[2]=f2b(a[2]); ua[3]=f2b(a[3]);
    ub[0]=f2b(b[0]); ub[1]=f2b(b[1]); ub[2]=f2b(b[2]); ub[3]=f2b(b[3]);
    *(u16x4*)&d[j] = ua;
    *(u16x4*)&d[j + 4] = ub;
}

// ---------------- Kernel P: projections (partial-K GEMM, hybrid) ----------
// grid: (96 col-tiles, 8 K-chunks of 256), 256 threads = 4 waves.
// W staged to LDS with fully-coalesced sequential f32x4 loads (the R2 pattern
// that worked); A-fragments read directly from L2-resident bf16 X/h.
// LDS = 33.8 KB -> 4 blocks/CU.
__global__ __launch_bounds__(256) void proj_kernel(
    const unsigned short* __restrict__ Xbf, const unsigned short* __restrict__ Hbf,
    const float* __restrict__ w_ih, const float* __restrict__ w_hh,
    const float* __restrict__ wq, const float* __restrict__ wk,
    const float* __restrict__ wv, float* __restrict__ part)
{
    int ct = blockIdx.x;            // 0..95
    int c  = blockIdx.y;            // 0..7
    int jbase = ct * 64;
    int o = jbase >> 10;            // 0..5
    if (o >= 3 && c >= 4) return;   // q/k/v have K=1024 (4 chunks)
    int jloc = jbase & 1023;

    const float* W; const unsigned short* A; int koff; int wrow;
    if (o < 3) {
        wrow = o * 1024 + jloc;
        if (c < 4) { W = w_ih; A = Xbf; koff = c * 256; }
        else       { W = w_hh; A = Hbf; koff = (c - 4) * 256; }
    } else {
        wrow = jloc;
        W = (o == 3) ? wq : (o == 4) ? wk : wv;
        A = Xbf; koff = c * 256;
    }

    // bf16 W tile, row-major [col][K], +8 pad (528B row stride)
    __shared__ unsigned short Bls[64][264];

    int tid = threadIdx.x;
    #pragma unroll
    for (int i = 0; i < 16; ++i) {          // 4096 f32x4 slots, coalesced
        int l = tid + i * 256;
        int r = l >> 6;                     // row 0..63
        int k4 = (l & 63) << 2;             // k 0..252 step 4
        f32x4 x = *(const f32x4*)&W[(size_t)(wrow + r) * 1024 + koff + k4];
        u16x4 u; u[0]=f2b(x[0]); u[1]=f2b(x[1]); u[2]=f2b(x[2]); u[3]=f2b(x[3]);
        *(u16x4*)&Bls[r][k4] = u;
    }
    __syncthreads();

    int lane = tid & 63;
    int w    = tid >> 6;            // wave -> col group
    int cn16 = lane & 15;
    int kg   = lane >> 4;           // 0..3

    f32x4 acc[4];
    #pragma unroll
    for (int m = 0; m < 4; ++m) { acc[m][0]=0.f; acc[m][1]=0.f; acc[m][2]=0.f; acc[m][3]=0.f; }

    #pragma unroll
    for (int ks = 0; ks < 8; ++ks) {
        int kb = ks * 32 + kg * 8;
        short8 bf = *(const short8*)&Bls[w * 16 + cn16][kb];
        #pragma unroll
        for (int m = 0; m < 4; ++m) {
            short8 af = *(const short8*)&A[(size_t)(m * 16 + cn16) * 1024 + koff + kb];
            acc[m] = __builtin_amdgcn_mfma_f32_16x16x32_bf16(af, bf, acc[m], 0, 0, 0);
        }
    }

    // D layout: col = lane&15, row(batch) = kg*4 + reg (+ m*16)
    #pragma unroll
    for (int m = 0; m < 4; ++m) {
        #pragma unroll
        for (int r = 0; r < 4; ++r) {
            int b = m * 16 + kg * 4 + r;
            part[((size_t)c * 64 + b) * NCOL + jbase + w * 16 + cn16] = acc[m][r];
        }
    }
}

// ---------------- Kernel U: c_new = f*c + (i*v)*k, fused act + q-row sums ---
// grid: (16 row-tiles of 64, 64 batches), 256 threads, 4 cols/thread.
// Prologue reduces part directly (gate activations recomputed per block from
// L3-resident part) -- no separate act kernel/buffer.
__global__ __launch_bounds__(256) void update_kernel(
    const float* __restrict__ c_in, const float* __restrict__ part,
    const float* __restrict__ bias, const float* __restrict__ wq_b,
    const float* __restrict__ wk_b, const float* __restrict__ wv_b,
    float* __restrict__ c_out, float* __restrict__ hpart)
{
    int t = blockIdx.x;            // 0..15
    int b = blockIdx.y;            // 0..63
    int tid = threadIdx.x;
    int col = tid * 4;

    __shared__ float fs[64], ivs[64], qvs[64];

    // k row: reduce 4 qkv chunks (coalesced, L3-hit)
    f32x4 k4; k4[0]=0.f; k4[1]=0.f; k4[2]=0.f; k4[3]=0.f;
    #pragma unroll
    for (int c = 0; c < 4; ++c)
        k4 += *(const f32x4*)&part[((size_t)c * 64 + b) * NCOL + 4096 + col];
    k4 += *(const f32x4*)&wk_b[col];

    if (tid < 64) {
        int hrow = t * 64 + tid;
        float ig = 0.f, fg = 0.f, qg = 0.f, vg = 0.f;
        #pragma unroll
        for (int c = 0; c < 8; ++c) {
            const float* pb = &part[((size_t)c * 64 + b) * NCOL];
            ig += pb[hrow];
            fg += pb[1024 + hrow];
            if (c < 4) { qg += pb[3072 + hrow]; vg += pb[5120 + hrow]; }
        }
        ig = expf(ig + bias[hrow]);
        fg = expf(fg + bias[1024 + hrow]);
        qg += wq_b[hrow];
        vg += wv_b[hrow];
        fs[tid] = fg; ivs[tid] = ig * vg; qvs[tid] = qg;
    }
    __syncthreads();

    f32x4 acc; acc[0]=0.f; acc[1]=0.f; acc[2]=0.f; acc[3]=0.f;
    size_t base = ((size_t)b * 1024 + (size_t)t * 64) * 1024 + col;

    #pragma unroll 8
    for (int hh = 0; hh < 64; ++hh) {
        f32x4 c4 = __builtin_nontemporal_load((const f32x4*)(c_in + base + (size_t)hh * 1024));
        float f = fs[hh], iv = ivs[hh], qv = qvs[hh];
        f32x4 cn = f * c4 + iv * k4;
        __builtin_nontemporal_store(cn, (f32x4*)(c_out + base + (size_t)hh * 1024));
        acc += qv * cn;
    }
    *(f32x4*)&hpart[((size_t)b * 16 + t) * 1024 + col] = acc;
}

// ---------------- Kernel R: h_new = o_g * sum_t hpart (o_g from part) -------
__global__ __launch_bounds__(256) void readout_kernel(
    const float* __restrict__ hpart, const float* __restrict__ part,
    const float* __restrict__ bias, float* __restrict__ h_new)
{
    int idx = blockIdx.x * 256 + threadIdx.x;   // 0..65536
    int b = idx >> 10, j = idx & 1023;
    float og = 0.f;
    #pragma unroll
    for (int c = 0; c < 8; ++c)
        og += part[((size_t)c * 64 + b) * NCOL + 2048 + j];
    og = 1.f / (1.f + expf(-(og + bias[2048 + j])));
    float s = 0.f;
    #pragma unroll
    for (int t = 0; t < 16; ++t)
        s += hpart[((size_t)b * 16 + t) * 1024 + j];
    h_new[idx] = og * s;
}

extern "C" void kernel_launch(void* const* d_in, const int* in_sizes, int n_in,
                              void* d_out, int out_size, void* d_ws, size_t ws_size,
                              hipStream_t stream)
{
    (void)in_sizes; (void)n_in; (void)out_size; (void)ws_size;
    const float* input = (const float*)d_in[0];   // [64,1024]
    const float* hvec  = (const float*)d_in[1];   // [64,1024]
    const float* c_in  = (const float*)d_in[2];   // [64,1024,1024]
    const float* w_ih  = (const float*)d_in[3];   // [3072,1024]
    const float* w_hh  = (const float*)d_in[4];   // [3072,1024]
    const float* bias  = (const float*)d_in[5];   // [3072]
    const float* wq_w  = (const float*)d_in[6];   // [1024,1024]
    const float* wq_b  = (const float*)d_in[7];
    const float* wk_w  = (const float*)d_in[8];
    const float* wk_b  = (const float*)d_in[9];
    const float* wv_w  = (const float*)d_in[10];
    const float* wv_b  = (const float*)d_in[11];

    float* out   = (float*)d_out;
    float* h_new = out;                 // [64,1024]
    float* c_new = out + 64 * 1024;     // [64,1024,1024]

    float* ws    = (float*)d_ws;
    float* part  = ws;                                   // 8*64*6144 floats
    float* hpart = part + (size_t)8 * 64 * NCOL;         // 64*16*1024
    unsigned short* xbf = (unsigned short*)(hpart + (size_t)64 * 16 * 1024);
    unsigned short* hbf = xbf + 64 * 1024;

    cvt_kernel<<<64, 256, 0, stream>>>(input, hvec, xbf, hbf);
    proj_kernel<<<dim3(96, 8), 256, 0, stream>>>(xbf, hbf, w_ih, w_hh,
                                                 wq_w, wk_w, wv_w, part);
    update_kernel<<<dim3(16, 64), 256, 0, stream>>>(c_in, part, bias, wq_b,
                                                    wk_b, wv_b, c_new, hpart);
    readout_kernel<<<(64 * 1024) / 256, 256, 0, stream>>>(hpart, part, bias, h_new);
}

// Round 7
// 124.151 us; speedup vs baseline: 1.1022x; 1.0764x over previous
//
#include <hip/hip_runtime.h>
#include <hip/hip_bf16.h>
#include <cstdint>

// Problem: B=64, D=1024, H=1024.
// act columns (6144): [0,1024) i_g | [1024,2048) f_g | [2048,3072) o_g
//                     [3072,4096) q | [4096,5120) k  | [5120,6144) v
// part layout: part[c][b][j], c = K-chunk of 256 (gates: 8 chunks = ih+hh;
// qkv: chunks 0..3 only)

#define NCOL 6144

typedef __attribute__((ext_vector_type(8))) short short8;
typedef __attribute__((ext_vector_type(4))) float f32x4;
typedef __attribute__((ext_vector_type(4))) unsigned short u16x4;

static __device__ __forceinline__ unsigned short f2b(float f) {
    union { float f; uint32_t u; } v; v.f = f;
    uint32_t r = (v.u + 0x7FFFu + ((v.u >> 16) & 1u)) >> 16;  // RNE
    return (unsigned short)r;
}

// ---------------- Kernel P: projections via bf16 MFMA (partial-K GEMM) ------
// R2-proven structure: grid (96 col-tiles, 8 K-chunks of 256), 256 thr = 4 waves.
// Both A (X/h) and B (W) tiles staged to LDS with fully-coalesced sequential
// f32x4 loads + f2b conversion. Wave w owns cols jbase+w*16..+15.
__global__ __launch_bounds__(256) void proj_kernel(
    const float* __restrict__ input, const float* __restrict__ hvec,
    const float* __restrict__ w_ih, const float* __restrict__ w_hh,
    const float* __restrict__ wq, const float* __restrict__ wk,
    const float* __restrict__ wv, float* __restrict__ part)
{
    int ct = blockIdx.x;            // 0..95
    int c  = blockIdx.y;            // 0..7
    int jbase = ct * 64;
    int o = jbase >> 10;            // which output (0..5)
    if (o >= 3 && c >= 4) return;   // q/k/v have only K=1024 (4 chunks)
    int jloc = jbase & 1023;

    const float* W; const float* src; int koff; int wrow;
    if (o < 3) {
        wrow = o * 1024 + jloc;
        if (c < 4) { W = w_ih; src = input; koff = c * 256; }
        else       { W = w_hh; src = hvec;  koff = (c - 4) * 256; }
    } else {
        wrow = jloc;
        W = (o == 3) ? wq : (o == 4) ? wk : wv;
        src = input; koff = c * 256;
    }

    // bf16 tiles, row-major [row][K], +8 pad => 528B row stride (2-way = free)
    __shared__ unsigned short Als[64][264];   // X/h: 64 batches x 256 K
    __shared__ unsigned short Bls[64][264];   // W:   64 cols    x 256 K

    int tid = threadIdx.x;
    #pragma unroll
    for (int i = 0; i < 16; ++i) {          // stage A: 4096 f32x4, coalesced
        int l = tid + i * 256;
        int r = l >> 6;                     // row 0..63
        int k4 = (l & 63) << 2;             // k 0..252 step 4
        f32x4 x = *(const f32x4*)&src[(size_t)r * 1024 + koff + k4];
        u16x4 u; u[0]=f2b(x[0]); u[1]=f2b(x[1]); u[2]=f2b(x[2]); u[3]=f2b(x[3]);
        *(u16x4*)&Als[r][k4] = u;
    }
    #pragma unroll
    for (int i = 0; i < 16; ++i) {          // stage B: coalesced
        int l = tid + i * 256;
        int r = l >> 6;
        int k4 = (l & 63) << 2;
        f32x4 x = *(const f32x4*)&W[(size_t)(wrow + r) * 1024 + koff + k4];
        u16x4 u; u[0]=f2b(x[0]); u[1]=f2b(x[1]); u[2]=f2b(x[2]); u[3]=f2b(x[3]);
        *(u16x4*)&Bls[r][k4] = u;
    }
    __syncthreads();

    int lane = tid & 63;
    int w    = tid >> 6;                    // wave -> col group
    int cn16 = lane & 15;
    int kg   = lane >> 4;                   // 0..3

    f32x4 acc[4];
    #pragma unroll
    for (int m = 0; m < 4; ++m) { acc[m][0]=0.f; acc[m][1]=0.f; acc[m][2]=0.f; acc[m][3]=0.f; }

    #pragma unroll
    for (int ks = 0; ks < 8; ++ks) {
        int kb = ks * 32 + kg * 8;          // 16B-aligned
        short8 bf = *(const short8*)&Bls[w * 16 + cn16][kb];
        #pragma unroll
        for (int m = 0; m < 4; ++m) {
            short8 af = *(const short8*)&Als[m * 16 + cn16][kb];
            acc[m] = __builtin_amdgcn_mfma_f32_16x16x32_bf16(af, bf, acc[m], 0, 0, 0);
        }
    }

    // D layout: col = lane&15, row(batch) = kg*4 + reg (+ m*16)
    #pragma unroll
    for (int m = 0; m < 4; ++m) {
        #pragma unroll
        for (int r = 0; r < 4; ++r) {
            int b = m * 16 + kg * 4 + r;
            part[((size_t)c * 64 + b) * NCOL + jbase + w * 16 + cn16] = acc[m][r];
        }
    }
}

// ---------------- Kernel A: reduce chunks + bias + activation (float4) ------
__global__ __launch_bounds__(256) void act_kernel(
    const float* __restrict__ part, const float* __restrict__ bias,
    const float* __restrict__ wq_b, const float* __restrict__ wk_b,
    const float* __restrict__ wv_b, float* __restrict__ act)
{
    int idx4 = blockIdx.x * 256 + threadIdx.x;   // 0..64*6144/4
    int b = idx4 / (NCOL / 4);
    int j = (idx4 - b * (NCOL / 4)) * 4;
    int nc = (j < 3072) ? 8 : 4;
    f32x4 s; s[0]=0.f; s[1]=0.f; s[2]=0.f; s[3]=0.f;
    for (int cc = 0; cc < nc; ++cc)
        s += *(const f32x4*)&part[((size_t)cc * 64 + b) * NCOL + j];
    const float* bp;
    if (j < 3072) bp = bias + j;
    else if (j < 4096) bp = wq_b + (j - 3072);
    else if (j < 5120) bp = wk_b + (j - 4096);
    else bp = wv_b + (j - 5120);
    s += *(const f32x4*)bp;
    f32x4 r;
    if (j < 2048) {
        r[0] = expf(s[0]); r[1] = expf(s[1]); r[2] = expf(s[2]); r[3] = expf(s[3]);
    } else if (j < 3072) {
        r[0] = 1.f/(1.f+expf(-s[0])); r[1] = 1.f/(1.f+expf(-s[1]));
        r[2] = 1.f/(1.f+expf(-s[2])); r[3] = 1.f/(1.f+expf(-s[3]));
    } else {
        r = s;
    }
    *(f32x4*)&act[(size_t)b * NCOL + j] = r;
}

// ---------------- Kernel U: c_new = f*c + (i*v)*k, fused q-weighted row sums -
// grid: (16 row-tiles of 64, 64 batches), 256 threads, 4 cols/thread.
// R2-style: gate scalars preloaded from act (cheap L2 hits), then pure
// nt-streamed 537 MB loop.
__global__ __launch_bounds__(256) void update_kernel(
    const float* __restrict__ c_in, const float* __restrict__ act,
    float* __restrict__ c_out, float* __restrict__ hpart)
{
    int t = blockIdx.x;            // 0..15
    int b = blockIdx.y;            // 0..63
    int tid = threadIdx.x;
    const float* arow = act + (size_t)b * NCOL;

    __shared__ float fs[64], ivs[64], qvs[64];
    if (tid < 64) {
        int hrow = t * 64 + tid;
        fs[tid]  = arow[1024 + hrow];
        ivs[tid] = arow[hrow] * arow[5120 + hrow];
        qvs[tid] = arow[3072 + hrow];
    }
    int col = tid * 4;
    f32x4 k4 = *(const f32x4*)&arow[4096 + col];
    __syncthreads();

    f32x4 acc; acc[0]=0.f; acc[1]=0.f; acc[2]=0.f; acc[3]=0.f;
    size_t base = ((size_t)b * 1024 + (size_t)t * 64) * 1024 + col;

    #pragma unroll 8
    for (int hh = 0; hh < 64; ++hh) {
        f32x4 c4 = __builtin_nontemporal_load((const f32x4*)(c_in + base + (size_t)hh * 1024));
        float f = fs[hh], iv = ivs[hh], qv = qvs[hh];
        f32x4 cn = f * c4 + iv * k4;
        __builtin_nontemporal_store(cn, (f32x4*)(c_out + base + (size_t)hh * 1024));
        acc += qv * cn;
    }
    *(f32x4*)&hpart[((size_t)b * 16 + t) * 1024 + col] = acc;
}

// ---------------- Kernel R: h_new = o_g * sum_t hpart ----------------
__global__ __launch_bounds__(256) void readout_kernel(
    const float* __restrict__ hpart, const float* __restrict__ act,
    float* __restrict__ h_new)
{
    int idx = blockIdx.x * 256 + threadIdx.x;   // 0..65536
    int b = idx >> 10, j = idx & 1023;
    float s = 0.f;
    #pragma unroll
    for (int t = 0; t < 16; ++t)
        s += hpart[((size_t)b * 16 + t) * 1024 + j];
    h_new[idx] = act[(size_t)b * NCOL + 2048 + j] * s;
}

extern "C" void kernel_launch(void* const* d_in, const int* in_sizes, int n_in,
                              void* d_out, int out_size, void* d_ws, size_t ws_size,
                              hipStream_t stream)
{
    (void)in_sizes; (void)n_in; (void)out_size; (void)ws_size;
    const float* input = (const float*)d_in[0];   // [64,1024]
    const float* hvec  = (const float*)d_in[1];   // [64,1024]
    const float* c_in  = (const float*)d_in[2];   // [64,1024,1024]
    const float* w_ih  = (const float*)d_in[3];   // [3072,1024]
    const float* w_hh  = (const float*)d_in[4];   // [3072,1024]
    const float* bias  = (const float*)d_in[5];   // [3072]
    const float* wq_w  = (const float*)d_in[6];   // [1024,1024]
    const float* wq_b  = (const float*)d_in[7];
    const float* wk_w  = (const float*)d_in[8];
    const float* wk_b  = (const float*)d_in[9];
    const float* wv_w  = (const float*)d_in[10];
    const float* wv_b  = (const float*)d_in[11];

    float* out   = (float*)d_out;
    float* h_new = out;                 // [64,1024]
    float* c_new = out + 64 * 1024;     // [64,1024,1024]

    float* ws    = (float*)d_ws;
    float* part  = ws;                                   // 8*64*6144 floats
    float* act   = part + (size_t)8 * 64 * NCOL;         // 64*6144
    float* hpart = act + (size_t)64 * NCOL;              // 64*16*1024

    proj_kernel<<<dim3(96, 8), 256, 0, stream>>>(input, hvec, w_ih, w_hh,
                                                 wq_w, wk_w, wv_w, part);
    act_kernel<<<(64 * NCOL / 4) / 256, 256, 0, stream>>>(part, bias, wq_b, wk_b,
                                                          wv_b, act);
    update_kernel<<<dim3(16, 64), 256, 0, stream>>>(c_in, act, c_new, hpart);
    readout_kernel<<<(64 * 1024) / 256, 256, 0, stream>>>(hpart, act, h_new);
}

// Round 8
// 122.188 us; speedup vs baseline: 1.1199x; 1.0161x over previous
//
#include <hip/hip_runtime.h>
#include <hip/hip_bf16.h>
#include <cstdint>

// Problem: B=64, D=1024, H=1024.
// act columns (6144): [0,1024) i_g | [1024,2048) f_g | [2048,3072) o_g
//                     [3072,4096) q | [4096,5120) k  | [5120,6144) v
// part layout: part[c][b][j], c = K-chunk of 256 (gates: 8 chunks = ih+hh;
// qkv: chunks 0..3 only)

#define NCOL 6144

typedef __attribute__((ext_vector_type(8))) short short8;
typedef __attribute__((ext_vector_type(4))) float f32x4;
typedef __attribute__((ext_vector_type(4))) unsigned short u16x4;

static __device__ __forceinline__ unsigned short f2b(float f) {
    union { float f; uint32_t u; } v; v.f = f;
    uint32_t r = (v.u + 0x7FFFu + ((v.u >> 16) & 1u)) >> 16;  // RNE
    return (unsigned short)r;
}

// ---------------- Kernel P: projections via bf16 MFMA (partial-K GEMM) ------
// R2 shape: grid (96 col-tiles, 8 K-chunks of 256), 256 thr = 4 waves, both
// tiles LDS-staged with coalesced f32x4 loads. NEW: chunk processed as 4
// sub-steps of K=64 with double-buffered LDS (36.9 KB -> 4 blocks/CU) and
// next-slab global loads issued before current-step MFMAs.
__global__ __launch_bounds__(256) void proj_kernel(
    const float* __restrict__ input, const float* __restrict__ hvec,
    const float* __restrict__ w_ih, const float* __restrict__ w_hh,
    const float* __restrict__ wq, const float* __restrict__ wk,
    const float* __restrict__ wv, float* __restrict__ part)
{
    int ct = blockIdx.x;            // 0..95
    int c  = blockIdx.y;            // 0..7
    int jbase = ct * 64;
    int o = jbase >> 10;            // which output (0..5)
    if (o >= 3 && c >= 4) return;   // q/k/v have only K=1024 (4 chunks)
    int jloc = jbase & 1023;

    const float* W; const float* src; int koff; int wrow;
    if (o < 3) {
        wrow = o * 1024 + jloc;
        if (c < 4) { W = w_ih; src = input; koff = c * 256; }
        else       { W = w_hh; src = hvec;  koff = (c - 4) * 256; }
    } else {
        wrow = jloc;
        W = (o == 3) ? wq : (o == 4) ? wk : wv;
        src = input; koff = c * 256;
    }

    // bf16 sub-tiles [64 rows][64 K + 8 pad], double-buffered
    __shared__ unsigned short Als[2][64][72];
    __shared__ unsigned short Bls[2][64][72];

    int tid = threadIdx.x;
    int r0 = tid >> 4;              // staging row base 0..15 (+16*i)
    int kc = (tid & 15) << 2;       // float col 0..60

    f32x4 ra[4], rb[4];

    // prefetch sub-step 0
    #pragma unroll
    for (int i = 0; i < 4; ++i)
        ra[i] = *(const f32x4*)&src[(size_t)(r0 + 16 * i) * 1024 + koff + kc];
    #pragma unroll
    for (int i = 0; i < 4; ++i)
        rb[i] = *(const f32x4*)&W[(size_t)(wrow + r0 + 16 * i) * 1024 + koff + kc];
    #pragma unroll
    for (int i = 0; i < 4; ++i) {
        u16x4 u; u[0]=f2b(ra[i][0]); u[1]=f2b(ra[i][1]); u[2]=f2b(ra[i][2]); u[3]=f2b(ra[i][3]);
        *(u16x4*)&Als[0][r0 + 16 * i][kc] = u;
    }
    #pragma unroll
    for (int i = 0; i < 4; ++i) {
        u16x4 u; u[0]=f2b(rb[i][0]); u[1]=f2b(rb[i][1]); u[2]=f2b(rb[i][2]); u[3]=f2b(rb[i][3]);
        *(u16x4*)&Bls[0][r0 + 16 * i][kc] = u;
    }
    __syncthreads();

    int lane = tid & 63;
    int w    = tid >> 6;                    // wave -> col group
    int cn16 = lane & 15;
    int kg   = lane >> 4;                   // 0..3

    f32x4 acc[4];
    #pragma unroll
    for (int m = 0; m < 4; ++m) { acc[m][0]=0.f; acc[m][1]=0.f; acc[m][2]=0.f; acc[m][3]=0.f; }

    #pragma unroll
    for (int s = 0; s < 4; ++s) {
        // issue next sub-slab's global loads before this step's MFMAs
        if (s < 3) {
            int kof2 = koff + (s + 1) * 64 + kc;
            #pragma unroll
            for (int i = 0; i < 4; ++i)
                ra[i] = *(const f32x4*)&src[(size_t)(r0 + 16 * i) * 1024 + kof2];
            #pragma unroll
            for (int i = 0; i < 4; ++i)
                rb[i] = *(const f32x4*)&W[(size_t)(wrow + r0 + 16 * i) * 1024 + kof2];
        }

        int buf = s & 1;
        #pragma unroll
        for (int ks2 = 0; ks2 < 2; ++ks2) {
            int kb = ks2 * 32 + kg * 8;     // 16B-aligned
            short8 bf = *(const short8*)&Bls[buf][w * 16 + cn16][kb];
            #pragma unroll
            for (int m = 0; m < 4; ++m) {
                short8 af = *(const short8*)&Als[buf][m * 16 + cn16][kb];
                acc[m] = __builtin_amdgcn_mfma_f32_16x16x32_bf16(af, bf, acc[m], 0, 0, 0);
            }
        }

        if (s < 3) {
            int nb = (s + 1) & 1;
            #pragma unroll
            for (int i = 0; i < 4; ++i) {
                u16x4 u; u[0]=f2b(ra[i][0]); u[1]=f2b(ra[i][1]); u[2]=f2b(ra[i][2]); u[3]=f2b(ra[i][3]);
                *(u16x4*)&Als[nb][r0 + 16 * i][kc] = u;
            }
            #pragma unroll
            for (int i = 0; i < 4; ++i) {
                u16x4 u; u[0]=f2b(rb[i][0]); u[1]=f2b(rb[i][1]); u[2]=f2b(rb[i][2]); u[3]=f2b(rb[i][3]);
                *(u16x4*)&Bls[nb][r0 + 16 * i][kc] = u;
            }
        }
        __syncthreads();
    }

    // D layout: col = lane&15, row(batch) = kg*4 + reg (+ m*16)
    #pragma unroll
    for (int m = 0; m < 4; ++m) {
        #pragma unroll
        for (int r = 0; r < 4; ++r) {
            int b = m * 16 + kg * 4 + r;
            part[((size_t)c * 64 + b) * NCOL + jbase + w * 16 + cn16] = acc[m][r];
        }
    }
}

// ---------------- Kernel A: reduce chunks + bias + activation (float4) ------
__global__ __launch_bounds__(256) void act_kernel(
    const float* __restrict__ part, const float* __restrict__ bias,
    const float* __restrict__ wq_b, const float* __restrict__ wk_b,
    const float* __restrict__ wv_b, float* __restrict__ act)
{
    int idx4 = blockIdx.x * 256 + threadIdx.x;   // 0..64*6144/4
    int b = idx4 / (NCOL / 4);
    int j = (idx4 - b * (NCOL / 4)) * 4;
    int nc = (j < 3072) ? 8 : 4;
    f32x4 s; s[0]=0.f; s[1]=0.f; s[2]=0.f; s[3]=0.f;
    for (int cc = 0; cc < nc; ++cc)
        s += *(const f32x4*)&part[((size_t)cc * 64 + b) * NCOL + j];
    const float* bp;
    if (j < 3072) bp = bias + j;
    else if (j < 4096) bp = wq_b + (j - 3072);
    else if (j < 5120) bp = wk_b + (j - 4096);
    else bp = wv_b + (j - 5120);
    s += *(const f32x4*)bp;
    f32x4 r;
    if (j < 2048) {
        r[0] = expf(s[0]); r[1] = expf(s[1]); r[2] = expf(s[2]); r[3] = expf(s[3]);
    } else if (j < 3072) {
        r[0] = 1.f/(1.f+expf(-s[0])); r[1] = 1.f/(1.f+expf(-s[1]));
        r[2] = 1.f/(1.f+expf(-s[2])); r[3] = 1.f/(1.f+expf(-s[3]));
    } else {
        r = s;
    }
    *(f32x4*)&act[(size_t)b * NCOL + j] = r;
}

// ---------------- Kernel U: c_new = f*c + (i*v)*k, fused q-weighted row sums -
// grid: (16 row-tiles of 64, 64 batches), 256 threads, 4 cols/thread.
__global__ __launch_bounds__(256) void update_kernel(
    const float* __restrict__ c_in, const float* __restrict__ act,
    float* __restrict__ c_out, float* __restrict__ hpart)
{
    int t = blockIdx.x;            // 0..15
    int b = blockIdx.y;            // 0..63
    int tid = threadIdx.x;
    const float* arow = act + (size_t)b * NCOL;

    __shared__ float fs[64], ivs[64], qvs[64];
    if (tid < 64) {
        int hrow = t * 64 + tid;
        fs[tid]  = arow[1024 + hrow];
        ivs[tid] = arow[hrow] * arow[5120 + hrow];
        qvs[tid] = arow[3072 + hrow];
    }
    int col = tid * 4;
    f32x4 k4 = *(const f32x4*)&arow[4096 + col];
    __syncthreads();

    f32x4 acc; acc[0]=0.f; acc[1]=0.f; acc[2]=0.f; acc[3]=0.f;
    size_t base = ((size_t)b * 1024 + (size_t)t * 64) * 1024 + col;

    #pragma unroll 8
    for (int hh = 0; hh < 64; ++hh) {
        f32x4 c4 = __builtin_nontemporal_load((const f32x4*)(c_in + base + (size_t)hh * 1024));
        float f = fs[hh], iv = ivs[hh], qv = qvs[hh];
        f32x4 cn = f * c4 + iv * k4;
        __builtin_nontemporal_store(cn, (f32x4*)(c_out + base + (size_t)hh * 1024));
        acc += qv * cn;
    }
    *(f32x4*)&hpart[((size_t)b * 16 + t) * 1024 + col] = acc;
}

// ---------------- Kernel R: h_new = o_g * sum_t hpart ----------------
__global__ __launch_bounds__(256) void readout_kernel(
    const float* __restrict__ hpart, const float* __restrict__ act,
    float* __restrict__ h_new)
{
    int idx = blockIdx.x * 256 + threadIdx.x;   // 0..65536
    int b = idx >> 10, j = idx & 1023;
    float s = 0.f;
    #pragma unroll
    for (int t = 0; t < 16; ++t)
        s += hpart[((size_t)b * 16 + t) * 1024 + j];
    h_new[idx] = act[(size_t)b * NCOL + 2048 + j] * s;
}

extern "C" void kernel_launch(void* const* d_in, const int* in_sizes, int n_in,
                              void* d_out, int out_size, void* d_ws, size_t ws_size,
                              hipStream_t stream)
{
    (void)in_sizes; (void)n_in; (void)out_size; (void)ws_size;
    const float* input = (const float*)d_in[0];   // [64,1024]
    const float* hvec  = (const float*)d_in[1];   // [64,1024]
    const float* c_in  = (const float*)d_in[2];   // [64,1024,1024]
    const float* w_ih  = (const float*)d_in[3];   // [3072,1024]
    const float* w_hh  = (const float*)d_in[4];   // [3072,1024]
    const float* bias  = (const float*)d_in[5];   // [3072]
    const float* wq_w  = (const float*)d_in[6];   // [1024,1024]
    const float* wq_b  = (const float*)d_in[7];
    const float* wk_w  = (const float*)d_in[8];
    const float* wk_b  = (const float*)d_in[9];
    const float* wv_w  = (const float*)d_in[10];
    const float* wv_b  = (const float*)d_in[11];

    float* out   = (float*)d_out;
    float* h_new = out;                 // [64,1024]
    float* c_new = out + 64 * 1024;     // [64,1024,1024]

    float* ws    = (float*)d_ws;
    float* part  = ws;                                   // 8*64*6144 floats
    float* act   = part + (size_t)8 * 64 * NCOL;         // 64*6144
    float* hpart = act + (size_t)64 * NCOL;              // 64*16*1024

    proj_kernel<<<dim3(96, 8), 256, 0, stream>>>(input, hvec, w_ih, w_hh,
                                                 wq_w, wk_w, wv_w, part);
    act_kernel<<<(64 * NCOL / 4) / 256, 256, 0, stream>>>(part, bias, wq_b, wk_b,
                                                          wv_b, act);
    update_kernel<<<dim3(16, 64), 256, 0, stream>>>(c_in, act, c_new, hpart);
    readout_kernel<<<(64 * 1024) / 256, 256, 0, stream>>>(hpart, act, h_new);
}

// Round 9
// 122.096 us; speedup vs baseline: 1.1207x; 1.0008x over previous
//
#include <hip/hip_runtime.h>
#include <hip/hip_bf16.h>
#include <cstdint>

// Problem: B=64, D=1024, H=1024.
// act columns (6144): [0,1024) i_g | [1024,2048) f_g | [2048,3072) o_g
//                     [3072,4096) q | [4096,5120) k  | [5120,6144) v
// part layout (bf16): part[c][b][j], c = K-chunk of 256 (gates: 8 chunks;
// qkv: chunks 0..3 only)

#define NCOL 6144

typedef __attribute__((ext_vector_type(8))) short short8;
typedef __attribute__((ext_vector_type(4))) float f32x4;
typedef __attribute__((ext_vector_type(4))) unsigned short u16x4;

static __device__ __forceinline__ unsigned short f2bs(float f) {
    union { __hip_bfloat16 h; unsigned short s; } cv;
    cv.h = __float2bfloat16(f);          // RNE; compiler emits v_cvt_pk pairs
    return cv.s;
}
static __device__ __forceinline__ u16x4 cvt4(f32x4 x) {
    u16x4 u; u[0]=f2bs(x[0]); u[1]=f2bs(x[1]); u[2]=f2bs(x[2]); u[3]=f2bs(x[3]);
    return u;
}
static __device__ __forceinline__ float b2f(unsigned short s) {
    union { uint32_t u; float f; } v; v.u = ((uint32_t)s) << 16; return v.f;
}

// ---------------- Kernel P: projections via bf16 MFMA (partial-K GEMM) ------
// R8 structure (dbuf K=64 sub-steps), flattened 576-block grid, native cvt,
// bf16 part output.
__global__ __launch_bounds__(256) void proj_kernel(
    const float* __restrict__ input, const float* __restrict__ hvec,
    const float* __restrict__ w_ih, const float* __restrict__ w_hh,
    const float* __restrict__ wq, const float* __restrict__ wk,
    const float* __restrict__ wv, unsigned short* __restrict__ part)
{
    int bid = blockIdx.x;           // 0..575 (384 gate items + 192 qkv items)
    int ct, c;
    if (bid < 384) { ct = bid >> 3; c = bid & 7; }          // gate tiles 0..47
    else { int e = bid - 384; ct = 48 + (e >> 2); c = e & 3; } // qkv tiles
    int jbase = ct * 64;
    int o = jbase >> 10;            // 0..5
    int jloc = jbase & 1023;

    const float* W; const float* src; int koff; int wrow;
    if (o < 3) {
        wrow = o * 1024 + jloc;
        if (c < 4) { W = w_ih; src = input; koff = c * 256; }
        else       { W = w_hh; src = hvec;  koff = (c - 4) * 256; }
    } else {
        wrow = jloc;
        W = (o == 3) ? wq : (o == 4) ? wk : wv;
        src = input; koff = c * 256;
    }

    // bf16 sub-tiles [64 rows][64 K + 8 pad], double-buffered
    __shared__ unsigned short Als[2][64][72];
    __shared__ unsigned short Bls[2][64][72];

    int tid = threadIdx.x;
    int r0 = tid >> 4;              // staging row base 0..15 (+16*i)
    int kc = (tid & 15) << 2;       // float col 0..60

    f32x4 ra[4], rb[4];

    // prefetch sub-step 0
    #pragma unroll
    for (int i = 0; i < 4; ++i)
        ra[i] = *(const f32x4*)&src[(size_t)(r0 + 16 * i) * 1024 + koff + kc];
    #pragma unroll
    for (int i = 0; i < 4; ++i)
        rb[i] = *(const f32x4*)&W[(size_t)(wrow + r0 + 16 * i) * 1024 + koff + kc];
    #pragma unroll
    for (int i = 0; i < 4; ++i)
        *(u16x4*)&Als[0][r0 + 16 * i][kc] = cvt4(ra[i]);
    #pragma unroll
    for (int i = 0; i < 4; ++i)
        *(u16x4*)&Bls[0][r0 + 16 * i][kc] = cvt4(rb[i]);
    __syncthreads();

    int lane = tid & 63;
    int w    = tid >> 6;                    // wave -> col group
    int cn16 = lane & 15;
    int kg   = lane >> 4;                   // 0..3

    f32x4 acc[4];
    #pragma unroll
    for (int m = 0; m < 4; ++m) { acc[m][0]=0.f; acc[m][1]=0.f; acc[m][2]=0.f; acc[m][3]=0.f; }

    #pragma unroll
    for (int s = 0; s < 4; ++s) {
        if (s < 3) {                        // issue next sub-slab loads first
            int kof2 = koff + (s + 1) * 64 + kc;
            #pragma unroll
            for (int i = 0; i < 4; ++i)
                ra[i] = *(const f32x4*)&src[(size_t)(r0 + 16 * i) * 1024 + kof2];
            #pragma unroll
            for (int i = 0; i < 4; ++i)
                rb[i] = *(const f32x4*)&W[(size_t)(wrow + r0 + 16 * i) * 1024 + kof2];
        }

        int buf = s & 1;
        #pragma unroll
        for (int ks2 = 0; ks2 < 2; ++ks2) {
            int kb = ks2 * 32 + kg * 8;     // 16B-aligned
            short8 bf = *(const short8*)&Bls[buf][w * 16 + cn16][kb];
            #pragma unroll
            for (int m = 0; m < 4; ++m) {
                short8 af = *(const short8*)&Als[buf][m * 16 + cn16][kb];
                acc[m] = __builtin_amdgcn_mfma_f32_16x16x32_bf16(af, bf, acc[m], 0, 0, 0);
            }
        }

        if (s < 3) {
            int nb = (s + 1) & 1;
            #pragma unroll
            for (int i = 0; i < 4; ++i)
                *(u16x4*)&Als[nb][r0 + 16 * i][kc] = cvt4(ra[i]);
            #pragma unroll
            for (int i = 0; i < 4; ++i)
                *(u16x4*)&Bls[nb][r0 + 16 * i][kc] = cvt4(rb[i]);
        }
        __syncthreads();
    }

    // D layout: col = lane&15, row(batch) = kg*4 + reg (+ m*16); bf16 store
    #pragma unroll
    for (int m = 0; m < 4; ++m) {
        #pragma unroll
        for (int r = 0; r < 4; ++r) {
            int b = m * 16 + kg * 4 + r;
            part[((size_t)c * 64 + b) * NCOL + jbase + w * 16 + cn16] = f2bs(acc[m][r]);
        }
    }
}

// ---------------- Kernel A: reduce chunks + bias + activation ----------------
__global__ __launch_bounds__(256) void act_kernel(
    const unsigned short* __restrict__ part, const float* __restrict__ bias,
    const float* __restrict__ wq_b, const float* __restrict__ wk_b,
    const float* __restrict__ wv_b, float* __restrict__ act)
{
    int idx4 = blockIdx.x * 256 + threadIdx.x;   // 0..64*6144/4
    int b = idx4 / (NCOL / 4);
    int j = (idx4 - b * (NCOL / 4)) * 4;
    int nc = (j < 3072) ? 8 : 4;
    f32x4 s; s[0]=0.f; s[1]=0.f; s[2]=0.f; s[3]=0.f;
    for (int cc = 0; cc < nc; ++cc) {
        u16x4 u = *(const u16x4*)&part[((size_t)cc * 64 + b) * NCOL + j];
        s[0] += b2f(u[0]); s[1] += b2f(u[1]); s[2] += b2f(u[2]); s[3] += b2f(u[3]);
    }
    const float* bp;
    if (j < 3072) bp = bias + j;
    else if (j < 4096) bp = wq_b + (j - 3072);
    else if (j < 5120) bp = wk_b + (j - 4096);
    else bp = wv_b + (j - 5120);
    s += *(const f32x4*)bp;
    f32x4 r;
    if (j < 2048) {
        r[0] = expf(s[0]); r[1] = expf(s[1]); r[2] = expf(s[2]); r[3] = expf(s[3]);
    } else if (j < 3072) {
        r[0] = 1.f/(1.f+expf(-s[0])); r[1] = 1.f/(1.f+expf(-s[1]));
        r[2] = 1.f/(1.f+expf(-s[2])); r[3] = 1.f/(1.f+expf(-s[3]));
    } else {
        r = s;
    }
    *(f32x4*)&act[(size_t)b * NCOL + j] = r;
}

// ---------------- Kernel U: c_new = f*c + (i*v)*k, fused q-weighted row sums -
// grid: (16 row-tiles of 64, 64 batches), 256 threads, 4 cols/thread. (R8)
__global__ __launch_bounds__(256) void update_kernel(
    const float* __restrict__ c_in, const float* __restrict__ act,
    float* __restrict__ c_out, float* __restrict__ hpart)
{
    int t = blockIdx.x;            // 0..15
    int b = blockIdx.y;            // 0..63
    int tid = threadIdx.x;
    const float* arow = act + (size_t)b * NCOL;

    __shared__ float fs[64], ivs[64], qvs[64];
    if (tid < 64) {
        int hrow = t * 64 + tid;
        fs[tid]  = arow[1024 + hrow];
        ivs[tid] = arow[hrow] * arow[5120 + hrow];
        qvs[tid] = arow[3072 + hrow];
    }
    int col = tid * 4;
    f32x4 k4 = *(const f32x4*)&arow[4096 + col];
    __syncthreads();

    f32x4 acc; acc[0]=0.f; acc[1]=0.f; acc[2]=0.f; acc[3]=0.f;
    size_t base = ((size_t)b * 1024 + (size_t)t * 64) * 1024 + col;

    #pragma unroll 8
    for (int hh = 0; hh < 64; ++hh) {
        f32x4 c4 = __builtin_nontemporal_load((const f32x4*)(c_in + base + (size_t)hh * 1024));
        float f = fs[hh], iv = ivs[hh], qv = qvs[hh];
        f32x4 cn = f * c4 + iv * k4;
        __builtin_nontemporal_store(cn, (f32x4*)(c_out + base + (size_t)hh * 1024));
        acc += qv * cn;
    }
    *(f32x4*)&hpart[((size_t)b * 16 + t) * 1024 + col] = acc;
}

// ---------------- Kernel R: h_new = o_g * sum_t hpart ----------------
__global__ __launch_bounds__(256) void readout_kernel(
    const float* __restrict__ hpart, const float* __restrict__ act,
    float* __restrict__ h_new)
{
    int idx = blockIdx.x * 256 + threadIdx.x;   // 0..65536
    int b = idx >> 10, j = idx & 1023;
    float s = 0.f;
    #pragma unroll
    for (int t = 0; t < 16; ++t)
        s += hpart[((size_t)b * 16 + t) * 1024 + j];
    h_new[idx] = act[(size_t)b * NCOL + 2048 + j] * s;
}

extern "C" void kernel_launch(void* const* d_in, const int* in_sizes, int n_in,
                              void* d_out, int out_size, void* d_ws, size_t ws_size,
                              hipStream_t stream)
{
    (void)in_sizes; (void)n_in; (void)out_size; (void)ws_size;
    const float* input = (const float*)d_in[0];   // [64,1024]
    const float* hvec  = (const float*)d_in[1];   // [64,1024]
    const float* c_in  = (const float*)d_in[2];   // [64,1024,1024]
    const float* w_ih  = (const float*)d_in[3];   // [3072,1024]
    const float* w_hh  = (const float*)d_in[4];   // [3072,1024]
    const float* bias  = (const float*)d_in[5];   // [3072]
    const float* wq_w  = (const float*)d_in[6];   // [1024,1024]
    const float* wq_b  = (const float*)d_in[7];
    const float* wk_w  = (const float*)d_in[8];
    const float* wk_b  = (const float*)d_in[9];
    const float* wv_w  = (const float*)d_in[10];
    const float* wv_b  = (const float*)d_in[11];

    float* out   = (float*)d_out;
    float* h_new = out;                 // [64,1024]
    float* c_new = out + 64 * 1024;     // [64,1024,1024]

    // ws layout: part (bf16) | act (f32) | hpart (f32)
    unsigned short* part = (unsigned short*)d_ws;          // 8*64*6144 ushorts
    float* act   = (float*)(part + (size_t)8 * 64 * NCOL); // 64*6144 floats
    float* hpart = act + (size_t)64 * NCOL;                // 64*16*1024 floats

    proj_kernel<<<576, 256, 0, stream>>>(input, hvec, w_ih, w_hh,
                                         wq_w, wk_w, wv_w, part);
    act_kernel<<<(64 * NCOL / 4) / 256, 256, 0, stream>>>(part, bias, wq_b, wk_b,
                                                          wv_b, act);
    update_kernel<<<dim3(16, 64), 256, 0, stream>>>(c_in, act, c_new, hpart);
    readout_kernel<<<(64 * 1024) / 256, 256, 0, stream>>>(hpart, act, h_new);
}